// Round 6
// baseline (111.565 us; speedup 1.0000x reference)
//
#include <hip/hip_runtime.h>
#include <hip/hip_bf16.h>

// DEC ClusteringLayer: q[i][j] = (1/(1+||x_i-c_j||^2)) / rowsum, ALPHA=1.
// Round 6 hybrid: A (x, fp32) staged COALESCED through LDS in MFMA-fragment
// order (XOR-swizzled; conflict-free ds_read_b128), BK=128 -> 4 tiles, 4
// barriers; barriers are raw `lgkmcnt(0); s_barrier` so global prefetches stay
// in flight across them. B (clusters, bf16, L2-resident) pre-packed in fragment
// order, loaded straight to registers with depth-2 prefetch via 3 named sets.

typedef __attribute__((ext_vector_type(8))) short short8v;
typedef __attribute__((ext_vector_type(4))) float f32x4;

#define DDIM 512
#define KCL  256
#define BM   64
#define NT   512
#define NB   16          // bodies (k-chunks of 32)
#define BTILE 8192       // shorts per fragment-order B image (256x32)

__device__ __forceinline__ short f2bf(float f) {
    __hip_bfloat16 h = __float2bfloat16(f);
    return __builtin_bit_cast(short, h);
}

// ---- pre-kernel: blocks 0..63 pack clusters -> bf16 fragment-order images;
//      blocks 64..79 compute ||c||^2 ----
__global__ void prep(const float* __restrict__ cl, short* __restrict__ wsB,
                     float* __restrict__ wsC2) {
    const int t = threadIdx.x;
    if (blockIdx.x < 64) {
        const int u = blockIdx.x * 256 + t;
        const int img = u >> 10, gi = u & 1023;
        const int g = gi >> 6, lq = (gi >> 4) & 3, l15 = gi & 15;
        const float* src = cl + (size_t)(g * 16 + l15) * DDIM + img * 32 + lq * 8;
        float4 a = *(const float4*)src;
        float4 b = *(const float4*)(src + 4);
        short8v s;
        s[0]=f2bf(a.x); s[1]=f2bf(a.y); s[2]=f2bf(a.z); s[3]=f2bf(a.w);
        s[4]=f2bf(b.x); s[5]=f2bf(b.y); s[6]=f2bf(b.z); s[7]=f2bf(b.w);
        *(short8v*)&wsB[(size_t)u * 8] = s;
    } else {
        const int cidx = (blockIdx.x - 64) * 16 + (t >> 4);
        const int j = t & 15;
        const float* src = cl + (size_t)cidx * DDIM + j * 32;
        float s = 0.f;
#pragma unroll
        for (int i = 0; i < 8; ++i) {
            float4 v = ((const float4*)src)[i];
            s += v.x*v.x + v.y*v.y + v.z*v.z + v.w*v.w;
        }
        s += __shfl_xor(s, 1); s += __shfl_xor(s, 2);
        s += __shfl_xor(s, 4); s += __shfl_xor(s, 8);
        if (j == 0) wsC2[cidx] = s;
    }
}

#define BAR() asm volatile("s_waitcnt lgkmcnt(0)\ns_barrier" ::: "memory")

// ---- main: 64 rows x 256 clusters per block, 8 waves (2 row-grp x 4 col-grp) ----
__global__ __launch_bounds__(NT, 4)
void dec_main(const float* __restrict__ x, const short* __restrict__ wsB,
              const float* __restrict__ wsC2, float* __restrict__ out) {
    __shared__ __align__(16) short lA[2][8192];   // 2 x 16KB fragment-order A tiles
    __shared__ float s_x2[BM];
    __shared__ float s_rs[4][BM];

    const int t = threadIdx.x, lane = t & 63, w = t >> 6;
    const int rg = w >> 2, cg = w & 3;
    const int l15 = lane & 15, lq = lane >> 4;
    const int row0 = blockIdx.x * BM;

    // ---- staging geometry: thread t covers row t>>3, 16 consecutive floats ----
    const int srow = t >> 3;                  // 0..63
    const int scol = (t & 7) << 4;            // 0..112 floats
    const float* xs = x + (size_t)(row0 + srow) * DDIM + scol;
    const int skk  = scol >> 5;               // k-chunk 0..3 within tile
    const int slq  = (scol >> 3) & 3;         // 0 or 2
    const int slot0 = (skk * 4 + (srow >> 4)) * 64 + slq * 16 + (srow & 15);
    const int slot1 = slot0 + 16;             // second 8-float half -> lq+1
    const int sw0 = (slot0 ^ ((slot0 >> 4) & 7)) * 8;   // shorts
    const int sw1 = (slot1 ^ ((slot1 >> 4) & 7)) * 8;

    // B fragment base (coalesced lane*16B)
    const short* bb = wsB + (size_t)(cg * 4) * 512 + (size_t)lane * 8;

    f32x4 acc[2][4];
#pragma unroll
    for (int m = 0; m < 2; ++m)
#pragma unroll
        for (int n = 0; n < 4; ++n) acc[m][n] = (f32x4){0.f,0.f,0.f,0.f};
    float x2p = 0.f;

    short8v Sa[4], Sb[4], Sc[4];              // B prefetch, depth-2 rotation
    float4 F0, F1, F2, F3;                    // A staging regs (one tile slice)

#define LOADA(AT)                                            \
    {  F0 = *(const float4*)(xs + (AT) * 128);               \
       F1 = *(const float4*)(xs + (AT) * 128 + 4);           \
       F2 = *(const float4*)(xs + (AT) * 128 + 8);           \
       F3 = *(const float4*)(xs + (AT) * 128 + 12); }

#define LOADB(TT, S)                                         \
    {  const short* bt = bb + (size_t)(TT) * BTILE;          \
       S[0] = *(const short8v*)(bt);                         \
       S[1] = *(const short8v*)(bt + 512);                   \
       S[2] = *(const short8v*)(bt + 1024);                  \
       S[3] = *(const short8v*)(bt + 1536); }

#define CVTW(AT)                                                                 \
    {  short8v u, v;                                                             \
       u[0]=f2bf(F0.x); u[1]=f2bf(F0.y); u[2]=f2bf(F0.z); u[3]=f2bf(F0.w);       \
       u[4]=f2bf(F1.x); u[5]=f2bf(F1.y); u[6]=f2bf(F1.z); u[7]=f2bf(F1.w);       \
       v[0]=f2bf(F2.x); v[1]=f2bf(F2.y); v[2]=f2bf(F2.z); v[3]=f2bf(F2.w);       \
       v[4]=f2bf(F3.x); v[5]=f2bf(F3.y); v[6]=f2bf(F3.z); v[7]=f2bf(F3.w);       \
       x2p += F0.x*F0.x + F0.y*F0.y + F0.z*F0.z + F0.w*F0.w                      \
            + F1.x*F1.x + F1.y*F1.y + F1.z*F1.z + F1.w*F1.w                      \
            + F2.x*F2.x + F2.y*F2.y + F2.z*F2.z + F2.w*F2.w                      \
            + F3.x*F3.x + F3.y*F3.y + F3.z*F3.z + F3.w*F3.w;                     \
       short* dst = &lA[(AT) & 1][0];                                            \
       *(short8v*)&dst[sw0] = u;                                                 \
       *(short8v*)&dst[sw1] = v; }

#define BODY(BJ, BUF, SU, SI)                                                    \
    {  if ((BJ) + 2 < NB) LOADB((BJ) + 2, SI);                                   \
       short8v a0, a1;                                                           \
       {  const int s0 = (((BJ) & 3) * 4 + rg * 2) * 64 + lane;                  \
          const int s1 = s0 + 64;                                                \
          a0 = *(const short8v*)&(BUF)[(s0 ^ ((s0 >> 4) & 7)) * 8];              \
          a1 = *(const short8v*)&(BUF)[(s1 ^ ((s1 >> 4) & 7)) * 8]; }            \
       acc[0][0] = __builtin_amdgcn_mfma_f32_16x16x32_bf16(a0, SU[0], acc[0][0], 0,0,0); \
       acc[0][1] = __builtin_amdgcn_mfma_f32_16x16x32_bf16(a0, SU[1], acc[0][1], 0,0,0); \
       acc[0][2] = __builtin_amdgcn_mfma_f32_16x16x32_bf16(a0, SU[2], acc[0][2], 0,0,0); \
       acc[0][3] = __builtin_amdgcn_mfma_f32_16x16x32_bf16(a0, SU[3], acc[0][3], 0,0,0); \
       acc[1][0] = __builtin_amdgcn_mfma_f32_16x16x32_bf16(a1, SU[0], acc[1][0], 0,0,0); \
       acc[1][1] = __builtin_amdgcn_mfma_f32_16x16x32_bf16(a1, SU[1], acc[1][1], 0,0,0); \
       acc[1][2] = __builtin_amdgcn_mfma_f32_16x16x32_bf16(a1, SU[2], acc[1][2], 0,0,0); \
       acc[1][3] = __builtin_amdgcn_mfma_f32_16x16x32_bf16(a1, SU[3], acc[1][3], 0,0,0); }

    // ---- prologue: A(0) staged, A(1) in flight; B(0),B(1) in flight ----
    LOADA(0);
    LOADB(0, Sa); LOADB(1, Sb);
    CVTW(0);
    LOADA(1);
    BAR();
    // tile 0 (bodies 0..3 on lA[0]); use set bj%3, issue B(bj+2) into (bj+2)%3
    BODY(0,  lA[0], Sa, Sc);  BODY(1,  lA[0], Sb, Sa);
    BODY(2,  lA[0], Sc, Sb);  BODY(3,  lA[0], Sa, Sc);
    CVTW(1); LOADA(2); BAR();
    BODY(4,  lA[1], Sb, Sa);  BODY(5,  lA[1], Sc, Sb);
    BODY(6,  lA[1], Sa, Sc);  BODY(7,  lA[1], Sb, Sa);
    CVTW(2); LOADA(3); BAR();
    BODY(8,  lA[0], Sc, Sb);  BODY(9,  lA[0], Sa, Sc);
    BODY(10, lA[0], Sb, Sa);  BODY(11, lA[0], Sc, Sb);
    CVTW(3); BAR();
    BODY(12, lA[1], Sa, Sc);  BODY(13, lA[1], Sb, Sa);
    BODY(14, lA[1], Sc, Sa);  BODY(15, lA[1], Sa, Sa);

    // ---- ||x||^2: 8 staging threads per row ----
    x2p += __shfl_xor(x2p, 1); x2p += __shfl_xor(x2p, 2); x2p += __shfl_xor(x2p, 4);
    if ((t & 7) == 0) s_x2[srow] = x2p;
    __syncthreads();

    // ---- epilogue: d2 -> q_unnorm (C/D: col=l15, row=lq*4+r) ----
    float c2a[4];
#pragma unroll
    for (int n = 0; n < 4; ++n) c2a[n] = wsC2[cg*64 + n*16 + l15];

#pragma unroll
    for (int m = 0; m < 2; ++m)
#pragma unroll
        for (int n = 0; n < 4; ++n)
#pragma unroll
            for (int r = 0; r < 4; ++r) {
                const int rw = rg*32 + m*16 + lq*4 + r;
                float d2 = fmaxf(s_x2[rw] + c2a[n] - 2.0f * acc[m][n][r], 0.0f);
                acc[m][n][r] = 1.0f / (1.0f + d2);
            }

    // ---- row sums: 16-lane shuffle, per-cg slot (deterministic) ----
#pragma unroll
    for (int m = 0; m < 2; ++m)
#pragma unroll
        for (int r = 0; r < 4; ++r) {
            float p = acc[m][0][r] + acc[m][1][r] + acc[m][2][r] + acc[m][3][r];
            p += __shfl_xor(p, 1); p += __shfl_xor(p, 2);
            p += __shfl_xor(p, 4); p += __shfl_xor(p, 8);
            if (l15 == 0) s_rs[cg][rg*32 + m*16 + lq*4 + r] = p;
        }
    __syncthreads();

    // ---- normalize + store ----
#pragma unroll
    for (int m = 0; m < 2; ++m)
#pragma unroll
        for (int r = 0; r < 4; ++r) {
            const int rw = rg*32 + m*16 + lq*4 + r;
            const float rinv = 1.0f / (s_rs[0][rw] + s_rs[1][rw] + s_rs[2][rw] + s_rs[3][rw]);
            float* o = out + (size_t)(row0 + rw) * KCL + cg*64 + l15;
#pragma unroll
            for (int n = 0; n < 4; ++n)
                o[n * 16] = acc[m][n][r] * rinv;
        }
}

extern "C" void kernel_launch(void* const* d_in, const int* in_sizes, int n_in,
                              void* d_out, int out_size, void* d_ws, size_t ws_size,
                              hipStream_t stream) {
    const float* x  = (const float*)d_in[0];
    const float* cl = (const float*)d_in[1];
    float* out = (float*)d_out;
    short* wsB  = (short*)d_ws;
    float* wsC2 = (float*)((char*)d_ws + (size_t)NB * BTILE * sizeof(short)); // +256 KB

    prep<<<80, 256, 0, stream>>>(cl, wsB, wsC2);
    const int B = in_sizes[0] / DDIM;     // 65536
    dec_main<<<B / BM, NT, 0, stream>>>(x, wsB, wsC2, out);
}

// Round 7
// 61.354 us; speedup vs baseline: 1.8184x; 1.8184x over previous
//
#include <hip/hip_runtime.h>
#include <hip/hip_bf16.h>

// DEC ClusteringLayer: q[i][j] = (1/(1+||x_i-c_j||^2)) / rowsum, ALPHA=1.
// Round 7: ONE-BARRIER kernel. Whole 64x512 A-tile staged to LDS in fragment
// order (contiguous conflict-free ds_write AND ds_read: slot permutation done
// in the work assignment, not addresses), then 16 free-running MFMA bodies —
// no intra-loop barriers, no vmcnt(0) drains. B (clusters, bf16, L2-resident)
// pre-packed fragment-order, loaded direct to regs, depth-1 (two named sets).

typedef __attribute__((ext_vector_type(8))) short short8v;
typedef __attribute__((ext_vector_type(4))) float f32x4;

#define DDIM 512
#define KCL  256
#define BM   64
#define NT   512
#define BTILE 8192       // shorts per fragment-order B image (256 x 32)

__device__ __forceinline__ short f2bf(float f) {
    __hip_bfloat16 h = __float2bfloat16(f);
    return __builtin_bit_cast(short, h);
}

// ---- pre-kernel: blocks 0..63 pack clusters -> bf16 fragment-order images;
//      blocks 64..79 compute ||c||^2 ----
__global__ void prep(const float* __restrict__ cl, short* __restrict__ wsB,
                     float* __restrict__ wsC2) {
    const int t = threadIdx.x;
    if (blockIdx.x < 64) {
        const int u = blockIdx.x * 256 + t;
        const int img = u >> 10, gi = u & 1023;
        const int g = gi >> 6, lq = (gi >> 4) & 3, l15 = gi & 15;
        const float* src = cl + (size_t)(g * 16 + l15) * DDIM + img * 32 + lq * 8;
        float4 a = *(const float4*)src;
        float4 b = *(const float4*)(src + 4);
        short8v s;
        s[0]=f2bf(a.x); s[1]=f2bf(a.y); s[2]=f2bf(a.z); s[3]=f2bf(a.w);
        s[4]=f2bf(b.x); s[5]=f2bf(b.y); s[6]=f2bf(b.z); s[7]=f2bf(b.w);
        *(short8v*)&wsB[(size_t)u * 8] = s;
    } else {
        const int cidx = (blockIdx.x - 64) * 16 + (t >> 4);
        const int j = t & 15;
        const float* src = cl + (size_t)cidx * DDIM + j * 32;
        float s = 0.f;
#pragma unroll
        for (int i = 0; i < 8; ++i) {
            float4 v = ((const float4*)src)[i];
            s += v.x*v.x + v.y*v.y + v.z*v.z + v.w*v.w;
        }
        s += __shfl_xor(s, 1); s += __shfl_xor(s, 2);
        s += __shfl_xor(s, 4); s += __shfl_xor(s, 8);
        if (j == 0) wsC2[cidx] = s;
    }
}

#define BAR() asm volatile("s_waitcnt lgkmcnt(0)\ns_barrier" ::: "memory")

// ---- main: 64 rows x 256 clusters per block, 8 waves (2 row-grp x 4 col-grp) ----
__global__ __launch_bounds__(NT, 4)
void dec_main(const float* __restrict__ x, const short* __restrict__ wsB,
              const float* __restrict__ wsC2, float* __restrict__ out) {
    __shared__ __align__(16) short lA[32768];   // 64 KB: full A-tile, fragment order
    __shared__ float s_x2p[2][BM];              // two-slot row-norm partials
    __shared__ float s_rs[4][BM];

    const int t = threadIdx.x, lane = t & 63, w = t >> 6;
    const int rg = w >> 2, cg = w & 3;          // GEMM roles
    const int l15 = lane & 15, lq = lane >> 4;
    const int row0 = blockIdx.x * BM;

    // ---- staging assignment (permuted so LDS writes are contiguous):
    // thread (w,l), round c' writes LDS slot c'*512 + w*64 + l  (16B each),
    // which holds x[row (w&3)*16 + (l&15)][k (2c'+(w>>2))*32 + (l>>4)*8 ..+7].
    const int srowS = (w & 3) * 16 + l15;
    const int scolS = (w >> 2) * 32 + lq * 8;
    const float* xs = x + (size_t)(row0 + srowS) * DDIM + scolS;

    // B fragment base (coalesced lane*16B)
    const short* bb = wsB + (size_t)(cg * 4) * 512 + (size_t)lane * 8;

    float x2p = 0.f;

    // ---- issue ALL 16 staging loads up front (64 regs live, acc not yet) ----
    float4 G0a = *(const float4*)(xs +   0), G0b = *(const float4*)(xs +   4);
    float4 G1a = *(const float4*)(xs +  64), G1b = *(const float4*)(xs +  68);
    float4 G2a = *(const float4*)(xs + 128), G2b = *(const float4*)(xs + 132);
    float4 G3a = *(const float4*)(xs + 192), G3b = *(const float4*)(xs + 196);
    float4 G4a = *(const float4*)(xs + 256), G4b = *(const float4*)(xs + 260);
    float4 G5a = *(const float4*)(xs + 320), G5b = *(const float4*)(xs + 324);
    float4 G6a = *(const float4*)(xs + 384), G6b = *(const float4*)(xs + 388);
    float4 G7a = *(const float4*)(xs + 448), G7b = *(const float4*)(xs + 452);

    short8v Ba[4], Bb[4];
#define LOADB(TT, S)                                         \
    {  const short* bt = bb + (size_t)(TT) * BTILE;          \
       S[0] = *(const short8v*)(bt);                         \
       S[1] = *(const short8v*)(bt + 512);                   \
       S[2] = *(const short8v*)(bt + 1024);                  \
       S[3] = *(const short8v*)(bt + 1536); }

    LOADB(0, Ba);                                // in flight across the barrier

#define STG(CP, GA, GB)                                                          \
    {  short8v s;                                                                \
       s[0]=f2bf(GA.x); s[1]=f2bf(GA.y); s[2]=f2bf(GA.z); s[3]=f2bf(GA.w);       \
       s[4]=f2bf(GB.x); s[5]=f2bf(GB.y); s[6]=f2bf(GB.z); s[7]=f2bf(GB.w);       \
       x2p += GA.x*GA.x + GA.y*GA.y + GA.z*GA.z + GA.w*GA.w                      \
            + GB.x*GB.x + GB.y*GB.y + GB.z*GB.z + GB.w*GB.w;                     \
       *(short8v*)&lA[(CP) * 4096 + t * 8] = s; }

    STG(0, G0a, G0b); STG(1, G1a, G1b); STG(2, G2a, G2b); STG(3, G3a, G3b);
    STG(4, G4a, G4b); STG(5, G5a, G5b); STG(6, G6a, G6b); STG(7, G7a, G7b);

    // row-norm partial: sum over this row's 4 lq lanes (bits 4,5 of lane)
    x2p += __shfl_xor(x2p, 16); x2p += __shfl_xor(x2p, 32);
    if (lane < 16) s_x2p[w >> 2][(w & 3) * 16 + lane] = x2p;

    BAR();   // the ONE barrier: LDS (lgkm) drained; B(0) vmem stays in flight

    // ---- GEMM phase: free-running, 16 bodies, depth-1 B prefetch ----
    f32x4 acc[2][4];
#pragma unroll
    for (int m = 0; m < 2; ++m)
#pragma unroll
        for (int n = 0; n < 4; ++n) acc[m][n] = (f32x4){0.f,0.f,0.f,0.f};

    const short* aB = &lA[rg * 1024 + lane * 8];

#define BODY(KK, SU, SN)                                                         \
    {  if ((KK) + 1 < 16) LOADB((KK) + 1, SN);                                   \
       short8v a0 = *(const short8v*)&aB[(KK) * 2048];                           \
       short8v a1 = *(const short8v*)&aB[(KK) * 2048 + 512];                     \
       acc[0][0] = __builtin_amdgcn_mfma_f32_16x16x32_bf16(a0, SU[0], acc[0][0], 0,0,0); \
       acc[0][1] = __builtin_amdgcn_mfma_f32_16x16x32_bf16(a0, SU[1], acc[0][1], 0,0,0); \
       acc[0][2] = __builtin_amdgcn_mfma_f32_16x16x32_bf16(a0, SU[2], acc[0][2], 0,0,0); \
       acc[0][3] = __builtin_amdgcn_mfma_f32_16x16x32_bf16(a0, SU[3], acc[0][3], 0,0,0); \
       acc[1][0] = __builtin_amdgcn_mfma_f32_16x16x32_bf16(a1, SU[0], acc[1][0], 0,0,0); \
       acc[1][1] = __builtin_amdgcn_mfma_f32_16x16x32_bf16(a1, SU[1], acc[1][1], 0,0,0); \
       acc[1][2] = __builtin_amdgcn_mfma_f32_16x16x32_bf16(a1, SU[2], acc[1][2], 0,0,0); \
       acc[1][3] = __builtin_amdgcn_mfma_f32_16x16x32_bf16(a1, SU[3], acc[1][3], 0,0,0); }

    BODY( 0, Ba, Bb); BODY( 1, Bb, Ba); BODY( 2, Ba, Bb); BODY( 3, Bb, Ba);
    BODY( 4, Ba, Bb); BODY( 5, Bb, Ba); BODY( 6, Ba, Bb); BODY( 7, Bb, Ba);
    BODY( 8, Ba, Bb); BODY( 9, Bb, Ba); BODY(10, Ba, Bb); BODY(11, Bb, Ba);
    BODY(12, Ba, Bb); BODY(13, Bb, Ba); BODY(14, Ba, Bb); BODY(15, Bb, Ba);

    // ---- epilogue: d2 -> q_unnorm (C/D: col=l15, row=lq*4+r) ----
    float c2a[4];
#pragma unroll
    for (int n = 0; n < 4; ++n) c2a[n] = wsC2[cg*64 + n*16 + l15];

#pragma unroll
    for (int m = 0; m < 2; ++m)
#pragma unroll
        for (int n = 0; n < 4; ++n)
#pragma unroll
            for (int r = 0; r < 4; ++r) {
                const int rw = rg*32 + m*16 + lq*4 + r;
                const float x2v = s_x2p[0][rw] + s_x2p[1][rw];
                float d2 = fmaxf(x2v + c2a[n] - 2.0f * acc[m][n][r], 0.0f);
                acc[m][n][r] = 1.0f / (1.0f + d2);
            }

    // ---- row sums: 16-lane shuffle, per-cg slot (deterministic) ----
#pragma unroll
    for (int m = 0; m < 2; ++m)
#pragma unroll
        for (int r = 0; r < 4; ++r) {
            float p = acc[m][0][r] + acc[m][1][r] + acc[m][2][r] + acc[m][3][r];
            p += __shfl_xor(p, 1); p += __shfl_xor(p, 2);
            p += __shfl_xor(p, 4); p += __shfl_xor(p, 8);
            if (l15 == 0) s_rs[cg][rg*32 + m*16 + lq*4 + r] = p;
        }
    __syncthreads();

    // ---- normalize + store ----
#pragma unroll
    for (int m = 0; m < 2; ++m)
#pragma unroll
        for (int r = 0; r < 4; ++r) {
            const int rw = rg*32 + m*16 + lq*4 + r;
            const float rinv = 1.0f / (s_rs[0][rw] + s_rs[1][rw] + s_rs[2][rw] + s_rs[3][rw]);
            float* o = out + (size_t)(row0 + rw) * KCL + cg*64 + l15;
#pragma unroll
            for (int n = 0; n < 4; ++n)
                o[n * 16] = acc[m][n][r] * rinv;
        }
}

extern "C" void kernel_launch(void* const* d_in, const int* in_sizes, int n_in,
                              void* d_out, int out_size, void* d_ws, size_t ws_size,
                              hipStream_t stream) {
    const float* x  = (const float*)d_in[0];
    const float* cl = (const float*)d_in[1];
    float* out = (float*)d_out;
    short* wsB  = (short*)d_ws;
    float* wsC2 = (float*)((char*)d_ws + (size_t)16 * BTILE * sizeof(short)); // +256 KB

    prep<<<80, 256, 0, stream>>>(cl, wsB, wsC2);
    const int B = in_sizes[0] / DDIM;     // 65536
    dec_main<<<B / BM, NT, 0, stream>>>(x, wsB, wsC2, out);
}